// Round 3
// baseline (874.180 us; speedup 1.0000x reference)
//
#include <hip/hip_runtime.h>
#include <hip/hip_cooperative_groups.h>

namespace cg = cooperative_groups;

// Sinkhorn with ragged masks, factorized into scaling vectors:
//   A = s + EPS (inside block), R/C scaling vectors.
//   col update: C[j] = 1 / sum_{i<nr} A[i,j]*R[i]
//   row update: R[i] = 1 / sum_{j<nc} A[i,j]*C[j]
// v4: ONE cooperative kernel. 512 blocks x 512 threads (2 blocks/CU,
// co-resident). Block (ch,b) owns rows [ch*128,(ch+1)*128) of batch b.
// Phases: prep (fp32 col update #1 + write fp16 H into d_out) -> sync ->
// 4x { fold P->C in LDS (redundant per block), fused row+col sweep of H,
// sync } -> fold -> final (exact fp32 from s, fused last row update).
// P partials ping-pong between Pa/Pb so no sync is needed between the
// fold (read) and the partial write of the same pass.
// v3 multi-kernel path kept as fallback if cooperative launch fails.

#define BB 64
#define NN 1024
#define MM 1024
#define EPS 1e-4f

typedef _Float16 half_t;
typedef __attribute__((ext_vector_type(4))) _Float16 half4_t;
typedef __attribute__((ext_vector_type(8))) _Float16 half8_t;
typedef __attribute__((ext_vector_type(4))) float float4_t;
typedef __attribute__((ext_vector_type(2))) float float2_t;

// fold P (8 chunk partials) -> cld[j] = (j<nc) ? 1/sum : 0
__device__ __forceinline__ void foldC(const float* __restrict__ Pc,
                                      float* cld, int b, int nc, int t) {
  float s0 = 0.f, s1 = 0.f;
#pragma unroll
  for (int k = 0; k < 8; k++) {
    float2_t p = *(const float2_t*)(Pc + ((size_t)k * BB + b) * MM + t * 2);
    s0 += p.x;
    s1 += p.y;
  }
  cld[t * 2] = (t * 2 < nc) ? 1.f / s0 : 0.f;
  cld[t * 2 + 1] = (t * 2 + 1 < nc) ? 1.f / s1 : 0.f;
}

// block-reduce per-lane col partials (8 waves) and store this chunk's P row
__device__ __forceinline__ void colReduceStore(float (&red)[8][MM],
                                               const float* a0,
                                               const float* a1, int w, int l,
                                               int t, float* Pdst) {
#pragma unroll
  for (int k = 0; k < 8; k++) red[w][l * 8 + k] = a0[k];
#pragma unroll
  for (int k = 0; k < 8; k++) red[w][512 + l * 8 + k] = a1[k];
  __syncthreads();
  float s0 = 0.f, s1 = 0.f;
#pragma unroll
  for (int k = 0; k < 8; k++) {
    s0 += red[k][t * 2];
    s1 += red[k][t * 2 + 1];
  }
  float2_t o = {s0, s1};
  *(float2_t*)(Pdst + t * 2) = o;
}

__global__ __launch_bounds__(512, 4) void sink_coop(
    const float* __restrict__ s, const int* __restrict__ nrows,
    const int* __restrict__ ncols, float* __restrict__ out,
    float* __restrict__ Pa, float* __restrict__ Pb) {
  cg::grid_group grid = cg::this_grid();
  const int bid = blockIdx.x;
  const int b = bid & (BB - 1), ch = bid >> 6;
  const int nr = nrows[b], nc = ncols[b];
  const int t = threadIdx.x;
  const int l = t & 63, w = t >> 6;

  __shared__ float red[8][MM];  // 32KB col-reduce scratch
  __shared__ float cld[MM];     // 4KB C vector for batch b

  half_t* H = (half_t*)out;  // fp16 A in lower 128MB of d_out
  const size_t mat = (size_t)b * NN * MM;
  const bool hi = (512 + l * 8) < nc;  // lane's high col-group in block?
  const int rbase = ch * 128 + w;
  float* Pme_a = Pa + ((size_t)ch * BB + b) * MM;
  float* Pme_b = Pb + ((size_t)ch * BB + b) * MM;

  // ---- phase 0: prep. H=(half)(s+eps) (all cols, rows<nr), exact fp32
  // col partials with R=1 -> Pa.
  {
    float a0[8] = {0.f, 0.f, 0.f, 0.f, 0.f, 0.f, 0.f, 0.f};
    float a1[8] = {0.f, 0.f, 0.f, 0.f, 0.f, 0.f, 0.f, 0.f};
    const float* sp = s + mat + l * 8;
    half_t* hp = H + mat + l * 8;
#pragma unroll 4
    for (int r = 0; r < 16; r++) {
      int i = rbase + (r << 3);
      if (i < nr) {  // wave-uniform
        const float* srow = sp + (size_t)i * MM;
        half_t* hrow = hp + (size_t)i * MM;
        float f0[8], f1[8];
        {
          float4_t u = *(const float4_t*)srow;
          float4_t v = *(const float4_t*)(srow + 4);
          f0[0] = u.x + EPS; f0[1] = u.y + EPS; f0[2] = u.z + EPS;
          f0[3] = u.w + EPS; f0[4] = v.x + EPS; f0[5] = v.y + EPS;
          f0[6] = v.z + EPS; f0[7] = v.w + EPS;
        }
        {
          float4_t u = *(const float4_t*)(srow + 512);
          float4_t v = *(const float4_t*)(srow + 516);
          f1[0] = u.x + EPS; f1[1] = u.y + EPS; f1[2] = u.z + EPS;
          f1[3] = u.w + EPS; f1[4] = v.x + EPS; f1[5] = v.y + EPS;
          f1[6] = v.z + EPS; f1[7] = v.w + EPS;
        }
        half8_t h0, h1;
#pragma unroll
        for (int k = 0; k < 8; k++) h0[k] = (half_t)f0[k];
#pragma unroll
        for (int k = 0; k < 8; k++) h1[k] = (half_t)f1[k];
        *(half8_t*)hrow = h0;
        *(half8_t*)(hrow + 512) = h1;
#pragma unroll
        for (int k = 0; k < 8; k++) a0[k] += f0[k];
#pragma unroll
        for (int k = 0; k < 8; k++) a1[k] += f1[k];
      }
    }
    colReduceStore(red, a0, a1, w, l, t, Pme_a);
  }
  grid.sync();

  // ---- 4 fused middle passes (row update in-register, col update) ----
  float* Pc = Pa;
  float* Pme_n = Pme_b;
  float* Pme_c = Pme_a;
  for (int pass = 0; pass < 4; pass++) {
    foldC(Pc, cld, b, nc, t);
    __syncthreads();
    float c0[8], c1[8];
#pragma unroll
    for (int k = 0; k < 8; k++) c0[k] = cld[l * 8 + k];
#pragma unroll
    for (int k = 0; k < 8; k++) c1[k] = cld[512 + l * 8 + k];
    float a0[8] = {0.f, 0.f, 0.f, 0.f, 0.f, 0.f, 0.f, 0.f};
    float a1[8] = {0.f, 0.f, 0.f, 0.f, 0.f, 0.f, 0.f, 0.f};
    const half_t* hp = H + mat + l * 8;
#pragma unroll 4
    for (int r = 0; r < 16; r++) {
      int i = rbase + (r << 3);
      if (i < nr) {  // wave-uniform
        const half_t* hr = hp + (size_t)i * MM;
        half8_t h0 = *(const half8_t*)hr;
        float f0[8];
#pragma unroll
        for (int k = 0; k < 8; k++) f0[k] = (float)h0[k];
        float acc = f0[0] * c0[0] + f0[1] * c0[1] + f0[2] * c0[2] +
                    f0[3] * c0[3] + f0[4] * c0[4] + f0[5] * c0[5] +
                    f0[6] * c0[6] + f0[7] * c0[7];
        float f1[8];
        if (hi) {
          half8_t h1 = *(const half8_t*)(hr + 512);
#pragma unroll
          for (int k = 0; k < 8; k++) f1[k] = (float)h1[k];
          acc += f1[0] * c1[0] + f1[1] * c1[1] + f1[2] * c1[2] +
                 f1[3] * c1[3] + f1[4] * c1[4] + f1[5] * c1[5] +
                 f1[6] * c1[6] + f1[7] * c1[7];
        }
#pragma unroll
        for (int off = 32; off > 0; off >>= 1)
          acc += __shfl_xor(acc, off, 64);
        float rv = 1.f / acc;
#pragma unroll
        for (int k = 0; k < 8; k++) a0[k] += f0[k] * rv;
        if (hi) {
#pragma unroll
          for (int k = 0; k < 8; k++) a1[k] += f1[k] * rv;
        }
      }
    }
    colReduceStore(red, a0, a1, w, l, t, Pme_n);
    grid.sync();
    // ping-pong
    Pc = (pass & 1) ? Pa : Pb;
    float* tmp = Pme_n; Pme_n = Pme_c; Pme_c = tmp;
  }

  // ---- final: last row update from exact fp32 s, scaled output ----
  foldC(Pc, cld, b, nc, t);
  __syncthreads();
  {
    float c0[8], c1[8];
#pragma unroll
    for (int k = 0; k < 8; k++) c0[k] = cld[l * 8 + k];
#pragma unroll
    for (int k = 0; k < 8; k++) c1[k] = cld[512 + l * 8 + k];
    const float* sp = s + mat + l * 8;
    float* op = out + mat + l * 8;
    float4_t z = {0.f, 0.f, 0.f, 0.f};
#pragma unroll 2
    for (int r = 0; r < 16; r++) {
      int i = rbase + (r << 3);
      float* orow = op + (size_t)i * MM;
      if (i >= nr) {  // wave-uniform: zero rows beyond nr
        *(float4_t*)orow = z;
        *(float4_t*)(orow + 4) = z;
        *(float4_t*)(orow + 512) = z;
        *(float4_t*)(orow + 516) = z;
        continue;
      }
      const float* srow = sp + (size_t)i * MM;
      float f0[8], f1[8];
      {
        float4_t u = *(const float4_t*)srow;
        float4_t v = *(const float4_t*)(srow + 4);
        f0[0] = u.x + EPS; f0[1] = u.y + EPS; f0[2] = u.z + EPS;
        f0[3] = u.w + EPS; f0[4] = v.x + EPS; f0[5] = v.y + EPS;
        f0[6] = v.z + EPS; f0[7] = v.w + EPS;
      }
      float acc = f0[0] * c0[0] + f0[1] * c0[1] + f0[2] * c0[2] +
                  f0[3] * c0[3] + f0[4] * c0[4] + f0[5] * c0[5] +
                  f0[6] * c0[6] + f0[7] * c0[7];
      if (hi) {
        float4_t u = *(const float4_t*)(srow + 512);
        float4_t v = *(const float4_t*)(srow + 516);
        f1[0] = u.x + EPS; f1[1] = u.y + EPS; f1[2] = u.z + EPS;
        f1[3] = u.w + EPS; f1[4] = v.x + EPS; f1[5] = v.y + EPS;
        f1[6] = v.z + EPS; f1[7] = v.w + EPS;
        acc += f1[0] * c1[0] + f1[1] * c1[1] + f1[2] * c1[2] +
               f1[3] * c1[3] + f1[4] * c1[4] + f1[5] * c1[5] +
               f1[6] * c1[6] + f1[7] * c1[7];
      }
#pragma unroll
      for (int off = 32; off > 0; off >>= 1) acc += __shfl_xor(acc, off, 64);
      float rv = 1.f / acc;
      float4_t o;
      o.x = f0[0] * c0[0] * rv; o.y = f0[1] * c0[1] * rv;
      o.z = f0[2] * c0[2] * rv; o.w = f0[3] * c0[3] * rv;
      *(float4_t*)orow = o;
      o.x = f0[4] * c0[4] * rv; o.y = f0[5] * c0[5] * rv;
      o.z = f0[6] * c0[6] * rv; o.w = f0[7] * c0[7] * rv;
      *(float4_t*)(orow + 4) = o;
      if (hi) {  // C[j>=nc]==0 zeroes the in-group tail automatically
        o.x = f1[0] * c1[0] * rv; o.y = f1[1] * c1[1] * rv;
        o.z = f1[2] * c1[2] * rv; o.w = f1[3] * c1[3] * rv;
        *(float4_t*)(orow + 512) = o;
        o.x = f1[4] * c1[4] * rv; o.y = f1[5] * c1[5] * rv;
        o.z = f1[6] * c1[6] * rv; o.w = f1[7] * c1[7] * rv;
        *(float4_t*)(orow + 516) = o;
      } else {
        *(float4_t*)(orow + 512) = z;
        *(float4_t*)(orow + 516) = z;
      }
    }
  }
}

// ======================= v3 fallback path ==============================

__global__ __launch_bounds__(256) void prep_kernel(
    const float* __restrict__ s, const int* __restrict__ nrows,
    const int* __restrict__ ncols, half_t* __restrict__ H,
    float* __restrict__ P) {
  int b = blockIdx.z, rc = blockIdx.y, stripe = blockIdx.x;
  int nr = nrows[b], nc = ncols[b];
  float* Pp = P + ((size_t)rc * BB + b) * MM + stripe * 128;
  if (stripe * 128 >= nc) {
    if (threadIdx.x < 128) Pp[threadIdx.x] = 0.f;
    return;
  }
  int tc = threadIdx.x & 31, tr = threadIdx.x >> 5;
  int j0 = stripe * 128 + tc * 4;
  const float* sp = s + (size_t)b * NN * MM + j0;
  half_t* hp = H + (size_t)b * NN * MM + j0;
  float4_t acc = {0.f, 0.f, 0.f, 0.f};
  int base = rc * 128;
#pragma unroll
  for (int it = 0; it < 16; it++) {
    int i = base + it * 8 + tr;
    if (i < nr) {
      float4_t v = *(const float4_t*)(sp + (size_t)i * MM);
      v.x += EPS; v.y += EPS; v.z += EPS; v.w += EPS;
      half4_t h = {(half_t)v.x, (half_t)v.y, (half_t)v.z, (half_t)v.w};
      *(half4_t*)(hp + (size_t)i * MM) = h;
      acc.x += v.x; acc.y += v.y; acc.z += v.z; acc.w += v.w;
    }
  }
  __shared__ float lds[8][128];
  *(float4_t*)&lds[tr][tc * 4] = acc;
  __syncthreads();
  if (threadIdx.x < 128) {
    float s0 = 0.f;
#pragma unroll
    for (int k = 0; k < 8; k++) s0 += lds[k][threadIdx.x];
    Pp[threadIdx.x] = s0;
  }
}

__global__ __launch_bounds__(256) void creduce_kernel(
    const float* __restrict__ P, const int* __restrict__ ncols,
    float* __restrict__ C) {
  int b = blockIdx.y;
  int j = blockIdx.x * 256 + threadIdx.x;
  int nc = ncols[b];
  float s0 = 0.f;
#pragma unroll
  for (int k = 0; k < 8; k++) s0 += P[((size_t)k * BB + b) * MM + j];
  C[b * MM + j] = (j < nc) ? 1.f / s0 : 0.f;
}

__global__ __launch_bounds__(512) void fused_kernel(
    const half_t* __restrict__ H, const int* __restrict__ nrows,
    const int* __restrict__ ncols, const float* __restrict__ C,
    float* __restrict__ P) {
  int b = blockIdx.y, ch = blockIdx.x;
  int nr = nrows[b], nc = ncols[b];
  int l = threadIdx.x & 63, w = threadIdx.x >> 6;
  const float* Cp = C + b * MM;
  float c0[8], c1[8];
  *(float4_t*)&c0[0] = *(const float4_t*)(Cp + l * 8);
  *(float4_t*)&c0[4] = *(const float4_t*)(Cp + l * 8 + 4);
  *(float4_t*)&c1[0] = *(const float4_t*)(Cp + 512 + l * 8);
  *(float4_t*)&c1[4] = *(const float4_t*)(Cp + 512 + l * 8 + 4);
  bool hi = (512 + l * 8) < nc;
  const half_t* hp = H + (size_t)b * NN * MM + l * 8;
  float a0[8] = {0.f, 0.f, 0.f, 0.f, 0.f, 0.f, 0.f, 0.f};
  float a1[8] = {0.f, 0.f, 0.f, 0.f, 0.f, 0.f, 0.f, 0.f};
  int rbase = ch * 128 + w;
#pragma unroll 4
  for (int r = 0; r < 16; r++) {
    int i = rbase + (r << 3);
    if (i < nr) {
      const half_t* hr = hp + (size_t)i * MM;
      half8_t h0 = *(const half8_t*)hr;
      float f0[8];
#pragma unroll
      for (int k = 0; k < 8; k++) f0[k] = (float)h0[k];
      float acc = f0[0] * c0[0] + f0[1] * c0[1] + f0[2] * c0[2] +
                  f0[3] * c0[3] + f0[4] * c0[4] + f0[5] * c0[5] +
                  f0[6] * c0[6] + f0[7] * c0[7];
      float f1[8];
      if (hi) {
        half8_t h1 = *(const half8_t*)(hr + 512);
#pragma unroll
        for (int k = 0; k < 8; k++) f1[k] = (float)h1[k];
        acc += f1[0] * c1[0] + f1[1] * c1[1] + f1[2] * c1[2] +
               f1[3] * c1[3] + f1[4] * c1[4] + f1[5] * c1[5] +
               f1[6] * c1[6] + f1[7] * c1[7];
      }
#pragma unroll
      for (int off = 32; off > 0; off >>= 1) acc += __shfl_xor(acc, off, 64);
      float rv = 1.f / acc;
#pragma unroll
      for (int k = 0; k < 8; k++) a0[k] += f0[k] * rv;
      if (hi) {
#pragma unroll
        for (int k = 0; k < 8; k++) a1[k] += f1[k] * rv;
      }
    }
  }
  __shared__ float lds[8][MM];
#pragma unroll
  for (int k = 0; k < 8; k++) lds[w][l * 8 + k] = a0[k];
#pragma unroll
  for (int k = 0; k < 8; k++) lds[w][512 + l * 8 + k] = a1[k];
  __syncthreads();
  int t = threadIdx.x;
  float s0 = 0.f, s1 = 0.f;
#pragma unroll
  for (int k = 0; k < 8; k++) {
    s0 += lds[k][t * 2];
    s1 += lds[k][t * 2 + 1];
  }
  float2_t o = {s0, s1};
  *(float2_t*)(P + ((size_t)ch * BB + b) * MM + t * 2) = o;
}

__global__ __launch_bounds__(256) void final_kernel(
    const float* __restrict__ s, const int* __restrict__ nrows,
    const int* __restrict__ ncols, const float* __restrict__ C,
    float* __restrict__ out) {
  int b = blockIdx.y;
  int nr = nrows[b], nc = ncols[b];
  int w = threadIdx.x >> 6, l = threadIdx.x & 63;
  int i = blockIdx.x * 4 + w;
  float* op = out + ((size_t)b * NN + i) * MM;
  float4_t z = {0.f, 0.f, 0.f, 0.f};
  if (i >= nr) {
#pragma unroll
    for (int ch = 0; ch < 4; ch++) *(float4_t*)(op + ch * 256 + l * 4) = z;
    return;
  }
  const float* sp = s + ((size_t)b * NN + i) * MM;
  const float* Cp = C + b * MM;
  float4_t sv[4], cv[4];
  float acc = 0.f;
  int nch = (nc + 255) >> 8;
#pragma unroll
  for (int ch = 0; ch < 4; ch++) {
    if (ch < nch) {
      float4_t v = *(const float4_t*)(sp + ch * 256 + l * 4);
      v.x += EPS; v.y += EPS; v.z += EPS; v.w += EPS;
      sv[ch] = v;
      float4_t c = *(const float4_t*)(Cp + ch * 256 + l * 4);
      cv[ch] = c;
      acc += v.x * c.x + v.y * c.y + v.z * c.z + v.w * c.w;
    }
  }
#pragma unroll
  for (int off = 32; off > 0; off >>= 1) acc += __shfl_xor(acc, off, 64);
  float r = 1.f / acc;
#pragma unroll
  for (int ch = 0; ch < 4; ch++) {
    if (ch < nch) {
      float4_t o;
      o.x = sv[ch].x * cv[ch].x * r;
      o.y = sv[ch].y * cv[ch].y * r;
      o.z = sv[ch].z * cv[ch].z * r;
      o.w = sv[ch].w * cv[ch].w * r;
      *(float4_t*)(op + ch * 256 + l * 4) = o;
    } else {
      *(float4_t*)(op + ch * 256 + l * 4) = z;
    }
  }
}

extern "C" void kernel_launch(void* const* d_in, const int* in_sizes, int n_in,
                              void* d_out, int out_size, void* d_ws,
                              size_t ws_size, hipStream_t stream) {
  const float* s = (const float*)d_in[0];
  const int* nrows = (const int*)d_in[1];
  const int* ncols = (const int*)d_in[2];
  float* out = (float*)d_out;
  float* Pa = (float*)d_ws;         // [8][BB][MM]
  float* Pb = Pa + 8 * BB * MM;     // [8][BB][MM]
  float* C = Pb + 8 * BB * MM;      // [BB*MM] (fallback only)

  void* args[] = {(void*)&s, (void*)&nrows, (void*)&ncols,
                  (void*)&out, (void*)&Pa, (void*)&Pb};
  hipError_t err = hipLaunchCooperativeKernel(sink_coop, dim3(512), dim3(512),
                                              args, 0, stream);
  if (err != hipSuccess) {
    // fallback: v3 multi-kernel pipeline
    half_t* H = (half_t*)d_out;
    float* P = Pa;
    dim3 pgrid(8, 8, BB);
    dim3 dgrid(4, BB);
    dim3 ugrid(8, BB);
    dim3 fgrid(NN / 4, BB);
    prep_kernel<<<pgrid, 256, 0, stream>>>(s, nrows, ncols, H, P);
    creduce_kernel<<<dgrid, 256, 0, stream>>>(P, ncols, C);
    for (int t = 0; t < 4; t++) {
      fused_kernel<<<ugrid, 512, 0, stream>>>(H, nrows, ncols, C, P);
      creduce_kernel<<<dgrid, 256, 0, stream>>>(P, ncols, C);
    }
    final_kernel<<<fgrid, 256, 0, stream>>>(s, nrows, ncols, C, out);
  }
}